// Round 1
// baseline (3646.239 us; speedup 1.0000x reference)
//
#include <hip/hip_runtime.h>
#include <math.h>

#define N_NODES 50000
#define E_EDGES 800000
#define D_DIM   128
#define H_HEADS 8
#define C_CH    16
#define HID_DIM 512
#define ED_DIM  32

// ---- ordered-uint encoding for float atomicMax ----
__device__ __forceinline__ unsigned enc_f(float f) {
    unsigned u = __float_as_uint(f);
    return (u & 0x80000000u) ? ~u : (u | 0x80000000u);
}
__device__ __forceinline__ float dec_f(unsigned u) {
    return (u & 0x80000000u) ? __uint_as_float(u & 0x7FFFFFFFu)
                             : __uint_as_float(~u);
}

// ============================================================
// Kernel A: per-node FFN + residual + LayerNorm + xl/xr proj
// 8 nodes per 256-thread block.
// ============================================================
__global__ __launch_bounds__(256) void node_ffn_kernel(
    const float* __restrict__ h,
    const float* __restrict__ w1, const float* __restrict__ b1,
    const float* __restrict__ w2, const float* __restrict__ b2,
    const float* __restrict__ ln_g, const float* __restrict__ ln_b,
    const float* __restrict__ Wl, const float* __restrict__ bl,
    const float* __restrict__ Wr, const float* __restrict__ br,
    float* __restrict__ v_out, float* __restrict__ xl_out, float* __restrict__ xr_out)
{
    __shared__ float h_s[8][128];    // 4 KB
    __shared__ float hid_s[8][512];  // 16 KB
    __shared__ float v_s[8][128];    // 4 KB
    const int tid = threadIdx.x;
    const int n0 = blockIdx.x * 8;

    // load 8 h rows (contiguous 4 KB, fully coalesced)
    #pragma unroll
    for (int i = 0; i < 4; ++i) {
        int flat = tid + i * 256;
        h_s[flat >> 7][flat & 127] = h[n0 * 128 + flat];
    }
    __syncthreads();

    // hid = relu(h @ w1 + b1); thread owns columns j=tid, tid+256 for all 8 nodes
    {
        float acc0[8], acc1[8];
        #pragma unroll
        for (int n = 0; n < 8; ++n) { acc0[n] = 0.f; acc1[n] = 0.f; }
        const int jA = tid, jB = tid + 256;
        for (int d = 0; d < 128; ++d) {
            float wa = w1[d * HID_DIM + jA];   // coalesced across threads
            float wb = w1[d * HID_DIM + jB];
            #pragma unroll
            for (int n = 0; n < 8; ++n) {
                float hv = h_s[n][d];          // LDS broadcast
                acc0[n] += hv * wa;
                acc1[n] += hv * wb;
            }
        }
        float ba = b1[jA], bb = b1[jB];
        #pragma unroll
        for (int n = 0; n < 8; ++n) {
            hid_s[n][jA] = fmaxf(acc0[n] + ba, 0.f);
            hid_s[n][jB] = fmaxf(acc1[n] + bb, 0.f);
        }
    }
    __syncthreads();

    // u = hid @ w2 + b2; t = h + u  -> v_s
    {
        const int d = tid & 127;
        const int g = tid >> 7;       // 0/1 -> node groups 0-3 / 4-7
        float acc[4] = {0.f, 0.f, 0.f, 0.f};
        for (int j = 0; j < HID_DIM; ++j) {
            float wv = w2[j * 128 + d];       // coalesced
            #pragma unroll
            for (int i = 0; i < 4; ++i)
                acc[i] += hid_s[g * 4 + i][j] * wv;   // broadcast per wave
        }
        float b2d = b2[d];
        #pragma unroll
        for (int i = 0; i < 4; ++i)
            v_s[g * 4 + i][d] = h_s[g * 4 + i][d] + acc[i] + b2d;
    }
    __syncthreads();

    // LayerNorm of v_s rows; each wave owns one node per iteration
    {
        const int wv = tid >> 6, lane = tid & 63;
        #pragma unroll
        for (int p = 0; p < 2; ++p) {
            int node = p * 4 + wv;
            float x0 = v_s[node][lane], x1 = v_s[node][lane + 64];
            float s = x0 + x1, ss = x0 * x0 + x1 * x1;
            #pragma unroll
            for (int off = 1; off < 64; off <<= 1) {
                s  += __shfl_xor(s, off);
                ss += __shfl_xor(ss, off);
            }
            float mu = s * (1.f / 128.f);
            float var = ss * (1.f / 128.f) - mu * mu;
            float rs = rsqrtf(var + 1e-5f);
            float y0 = (x0 - mu) * rs * ln_g[lane] + ln_b[lane];
            float y1 = (x1 - mu) * rs * ln_g[lane + 64] + ln_b[lane + 64];
            v_s[node][lane] = y0;
            v_s[node][lane + 64] = y1;
            v_out[(size_t)(n0 + node) * 128 + lane] = y0;
            v_out[(size_t)(n0 + node) * 128 + lane + 64] = y1;
        }
    }
    __syncthreads();

    // xl = v @ Wl + bl ; xr = v @ Wr + br
    {
        const int d = tid & 127;
        const int g = tid >> 7;
        float accl[4] = {0.f, 0.f, 0.f, 0.f}, accr[4] = {0.f, 0.f, 0.f, 0.f};
        for (int k = 0; k < 128; ++k) {
            float wl = Wl[k * 128 + d];
            float wr = Wr[k * 128 + d];
            #pragma unroll
            for (int i = 0; i < 4; ++i) {
                float vv = v_s[g * 4 + i][k];
                accl[i] += vv * wl;
                accr[i] += vv * wr;
            }
        }
        float bld = bl[d], brd = br[d];
        #pragma unroll
        for (int i = 0; i < 4; ++i) {
            xl_out[(size_t)(n0 + g * 4 + i) * 128 + d] = accl[i] + bld;
            xr_out[(size_t)(n0 + g * 4 + i) * 128 + d] = accr[i] + brd;
        }
    }
}

// ============================================================
// Kernel B: per-edge logits + segment max (atomicMax on encoded uint)
// 16 edges per 256-thread block; 16 lanes per edge.
// ============================================================
__global__ __launch_bounds__(256) void edge_logits_kernel(
    const int* __restrict__ edge_index, const float* __restrict__ edge_attr,
    const float* __restrict__ We, const float* __restrict__ att,
    const float* __restrict__ xl, const float* __restrict__ xr,
    float* __restrict__ logits_out, unsigned* __restrict__ m)
{
    __shared__ float We_s[ED_DIM * 128];  // 16 KB
    __shared__ float att_s[128];
    __shared__ float ea_s[16][33];        // +1 pad: conflict-free
    const int tid = threadIdx.x;
    const int e0 = blockIdx.x * 16;

    for (int i = tid; i < ED_DIM * 128; i += 256) We_s[i] = We[i];
    if (tid < 128) att_s[tid] = att[tid];
    for (int i = tid; i < 16 * ED_DIM; i += 256)
        ea_s[i >> 5][i & 31] = edge_attr[(size_t)e0 * ED_DIM + i];
    __syncthreads();

    const int le = tid >> 4, l16 = tid & 15;
    const int e = e0 + le;
    const int src = edge_index[e];
    const int dst = edge_index[E_EDGES + e];
    const int d0 = l16 * 8;

    const float4* xlp = (const float4*)(xl + (size_t)src * 128 + d0);
    const float4* xrp = (const float4*)(xr + (size_t)dst * 128 + d0);
    float4 a0 = xlp[0], a1 = xlp[1];
    float4 r0 = xrp[0], r1 = xrp[1];
    float xv[8] = { a0.x + r0.x, a0.y + r0.y, a0.z + r0.z, a0.w + r0.w,
                    a1.x + r1.x, a1.y + r1.y, a1.z + r1.z, a1.w + r1.w };

    #pragma unroll 8
    for (int k = 0; k < ED_DIM; ++k) {
        float eak = ea_s[le][k];
        const float* Wrow = &We_s[k * 128 + d0];
        #pragma unroll
        for (int dd = 0; dd < 8; ++dd) xv[dd] += eak * Wrow[dd];
    }
    float p = 0.f;
    #pragma unroll
    for (int dd = 0; dd < 8; ++dd) {
        float x = xv[dd];
        x = (x > 0.f) ? x : 0.2f * x;      // leaky_relu 0.2
        p += x * att_s[d0 + dd];
    }
    p += __shfl_xor(p, 1);                 // combine the 2 lanes of each head
    if ((l16 & 1) == 0) {
        int hh = l16 >> 1;
        logits_out[(size_t)e * 8 + hh] = p;
        atomicMax(&m[(size_t)dst * 8 + hh], enc_f(p));
    }
}

// ============================================================
// Kernel C: ex = exp(logit - m[dst]) in place; den += ex
// ============================================================
__global__ __launch_bounds__(256) void edge_exp_kernel(
    const int* __restrict__ edge_index, const unsigned* __restrict__ m,
    float* __restrict__ exs, float* __restrict__ den)
{
    int id = blockIdx.x * 256 + threadIdx.x;   // [0, E*8)
    int e = id >> 3, hh = id & 7;
    int dst = edge_index[E_EDGES + e];
    float lg = exs[id];
    float md = dec_f(m[(size_t)dst * 8 + hh]);
    float ex = expf(lg - md);
    exs[id] = ex;
    atomicAdd(&den[(size_t)dst * 8 + hh], ex);
}

// ============================================================
// Kernel D: alpha = ex/den[dst]; w[dst] += xl[src]*alpha (atomics)
// 16 edges per block; 16 lanes per edge.
// ============================================================
__global__ __launch_bounds__(256) void edge_msg_kernel(
    const int* __restrict__ edge_index, const float* __restrict__ xl,
    const float* __restrict__ den, float* __restrict__ alpha,
    float* __restrict__ wacc)
{
    const int tid = threadIdx.x;
    const int e = blockIdx.x * 16 + (tid >> 4);
    const int l16 = tid & 15;
    const int hh = l16 >> 1;
    const int src = edge_index[e];
    const int dst = edge_index[E_EDGES + e];

    // both lanes of the pair read ex in lockstep before the single write
    float a = alpha[(size_t)e * 8 + hh] / den[(size_t)dst * 8 + hh];
    if ((l16 & 1) == 0) alpha[(size_t)e * 8 + hh] = a;

    const int d0 = l16 * 8;
    const float4* xlp = (const float4*)(xl + (size_t)src * 128 + d0);
    float4 a0 = xlp[0], a1 = xlp[1];
    float* wp = wacc + (size_t)dst * 128 + d0;
    atomicAdd(&wp[0], a0.x * a); atomicAdd(&wp[1], a0.y * a);
    atomicAdd(&wp[2], a0.z * a); atomicAdd(&wp[3], a0.w * a);
    atomicAdd(&wp[4], a1.x * a); atomicAdd(&wp[5], a1.y * a);
    atomicAdd(&wp[6], a1.z * a); atomicAdd(&wp[7], a1.w * a);
}

// ============================================================
// Kernel E: out = LayerNorm(w + bias_out + v), in place on out
// ============================================================
__global__ __launch_bounds__(128) void final_ln_kernel(
    const float* __restrict__ v, const float* __restrict__ bias_out,
    const float* __restrict__ ln_g, const float* __restrict__ ln_b,
    float* __restrict__ out)
{
    __shared__ float red[4];
    const int n = blockIdx.x, t = threadIdx.x;
    float x = out[(size_t)n * 128 + t] + bias_out[t] + v[(size_t)n * 128 + t];
    float s = x, ss = x * x;
    #pragma unroll
    for (int off = 1; off < 64; off <<= 1) {
        s  += __shfl_xor(s, off);
        ss += __shfl_xor(ss, off);
    }
    int wv = t >> 6;
    if ((t & 63) == 0) { red[wv * 2] = s; red[wv * 2 + 1] = ss; }
    __syncthreads();
    float ts = red[0] + red[2], tss = red[1] + red[3];
    float mu = ts * (1.f / 128.f);
    float var = tss * (1.f / 128.f) - mu * mu;
    float rs = rsqrtf(var + 1e-5f);
    out[(size_t)n * 128 + t] = (x - mu) * rs * ln_g[t] + ln_b[t];
}

// ============================================================
extern "C" void kernel_launch(void* const* d_in, const int* in_sizes, int n_in,
                              void* d_out, int out_size, void* d_ws, size_t ws_size,
                              hipStream_t stream)
{
    const float* h        = (const float*)d_in[0];
    const int*   edge_idx = (const int*)  d_in[1];
    const float* edge_attr= (const float*)d_in[2];
    const float* w1       = (const float*)d_in[3];
    const float* b1       = (const float*)d_in[4];
    const float* w2       = (const float*)d_in[5];
    const float* b2       = (const float*)d_in[6];
    const float* ln_g     = (const float*)d_in[7];
    const float* ln_b     = (const float*)d_in[8];
    const float* Wl       = (const float*)d_in[9];
    const float* bl       = (const float*)d_in[10];
    const float* Wr       = (const float*)d_in[11];
    const float* br       = (const float*)d_in[12];
    const float* We       = (const float*)d_in[13];
    const float* att      = (const float*)d_in[14];
    const float* bias_out = (const float*)d_in[15];

    float* out   = (float*)d_out;                       // [N,128]
    float* alpha = out + (size_t)N_NODES * 128;         // [E,8]

    float*    v   = (float*)d_ws;                       // [N,128]
    float*    xl  = v  + (size_t)N_NODES * 128;         // [N,128]
    float*    xr  = xl + (size_t)N_NODES * 128;         // [N,128]
    float*    den = xr + (size_t)N_NODES * 128;         // [N,8]
    unsigned* m   = (unsigned*)(den + (size_t)N_NODES * 8); // [N,8]

    // zero the accumulators; m -> 0x01010101 decodes to ~-1.69e38 (safe -inf)
    hipMemsetAsync(out, 0, (size_t)N_NODES * 128 * sizeof(float), stream);
    hipMemsetAsync(den, 0, (size_t)N_NODES * 8 * sizeof(float), stream);
    hipMemsetAsync(m, 0x01, (size_t)N_NODES * 8 * sizeof(unsigned), stream);

    node_ffn_kernel<<<N_NODES / 8, 256, 0, stream>>>(
        h, w1, b1, w2, b2, ln_g, ln_b, Wl, bl, Wr, br, v, xl, xr);
    edge_logits_kernel<<<E_EDGES / 16, 256, 0, stream>>>(
        edge_idx, edge_attr, We, att, xl, xr, alpha, m);
    edge_exp_kernel<<<E_EDGES * 8 / 256, 256, 0, stream>>>(
        edge_idx, m, alpha, den);
    edge_msg_kernel<<<E_EDGES / 16, 256, 0, stream>>>(
        edge_idx, xl, den, alpha, out);
    final_ln_kernel<<<N_NODES, 128, 0, stream>>>(
        v, bias_out, ln_g, ln_b, out);
}

// Round 2
// 988.079 us; speedup vs baseline: 3.6902x; 3.6902x over previous
//
#include <hip/hip_runtime.h>
#include <math.h>

#define N_NODES 50000
#define E_EDGES 800000
#define D_DIM   128
#define H_HEADS 8
#define C_CH    16
#define HID_DIM 512
#define ED_DIM  32

// ============================================================
// Kernel A: per-node FFN + residual + LayerNorm + xl/xr proj
// 8 nodes per 256-thread block.
// ============================================================
__global__ __launch_bounds__(256) void node_ffn_kernel(
    const float* __restrict__ h,
    const float* __restrict__ w1, const float* __restrict__ b1,
    const float* __restrict__ w2, const float* __restrict__ b2,
    const float* __restrict__ ln_g, const float* __restrict__ ln_b,
    const float* __restrict__ Wl, const float* __restrict__ bl,
    const float* __restrict__ Wr, const float* __restrict__ br,
    float* __restrict__ v_out, float* __restrict__ xl_out, float* __restrict__ xr_out)
{
    __shared__ float h_s[8][128];    // 4 KB
    __shared__ float hid_s[8][512];  // 16 KB
    __shared__ float v_s[8][128];    // 4 KB
    const int tid = threadIdx.x;
    const int n0 = blockIdx.x * 8;

    #pragma unroll
    for (int i = 0; i < 4; ++i) {
        int flat = tid + i * 256;
        h_s[flat >> 7][flat & 127] = h[n0 * 128 + flat];
    }
    __syncthreads();

    // hid = relu(h @ w1 + b1)
    {
        float acc0[8], acc1[8];
        #pragma unroll
        for (int n = 0; n < 8; ++n) { acc0[n] = 0.f; acc1[n] = 0.f; }
        const int jA = tid, jB = tid + 256;
        for (int d = 0; d < 128; ++d) {
            float wa = w1[d * HID_DIM + jA];
            float wb = w1[d * HID_DIM + jB];
            #pragma unroll
            for (int n = 0; n < 8; ++n) {
                float hv = h_s[n][d];
                acc0[n] += hv * wa;
                acc1[n] += hv * wb;
            }
        }
        float ba = b1[jA], bb = b1[jB];
        #pragma unroll
        for (int n = 0; n < 8; ++n) {
            hid_s[n][jA] = fmaxf(acc0[n] + ba, 0.f);
            hid_s[n][jB] = fmaxf(acc1[n] + bb, 0.f);
        }
    }
    __syncthreads();

    // u = hid @ w2 + b2; v_s = h + u
    {
        const int d = tid & 127;
        const int g = tid >> 7;
        float acc[4] = {0.f, 0.f, 0.f, 0.f};
        for (int j = 0; j < HID_DIM; ++j) {
            float wv = w2[j * 128 + d];
            #pragma unroll
            for (int i = 0; i < 4; ++i)
                acc[i] += hid_s[g * 4 + i][j] * wv;
        }
        float b2d = b2[d];
        #pragma unroll
        for (int i = 0; i < 4; ++i)
            v_s[g * 4 + i][d] = h_s[g * 4 + i][d] + acc[i] + b2d;
    }
    __syncthreads();

    // LayerNorm rows of v_s
    {
        const int wv = tid >> 6, lane = tid & 63;
        #pragma unroll
        for (int p = 0; p < 2; ++p) {
            int node = p * 4 + wv;
            float x0 = v_s[node][lane], x1 = v_s[node][lane + 64];
            float s = x0 + x1, ss = x0 * x0 + x1 * x1;
            #pragma unroll
            for (int off = 1; off < 64; off <<= 1) {
                s  += __shfl_xor(s, off);
                ss += __shfl_xor(ss, off);
            }
            float mu = s * (1.f / 128.f);
            float var = ss * (1.f / 128.f) - mu * mu;
            float rs = rsqrtf(var + 1e-5f);
            float y0 = (x0 - mu) * rs * ln_g[lane] + ln_b[lane];
            float y1 = (x1 - mu) * rs * ln_g[lane + 64] + ln_b[lane + 64];
            v_s[node][lane] = y0;
            v_s[node][lane + 64] = y1;
            v_out[(size_t)(n0 + node) * 128 + lane] = y0;
            v_out[(size_t)(n0 + node) * 128 + lane + 64] = y1;
        }
    }
    __syncthreads();

    // xl = v @ Wl + bl ; xr = v @ Wr + br
    {
        const int d = tid & 127;
        const int g = tid >> 7;
        float accl[4] = {0.f, 0.f, 0.f, 0.f}, accr[4] = {0.f, 0.f, 0.f, 0.f};
        for (int k = 0; k < 128; ++k) {
            float wl = Wl[k * 128 + d];
            float wr = Wr[k * 128 + d];
            #pragma unroll
            for (int i = 0; i < 4; ++i) {
                float vv = v_s[g * 4 + i][k];
                accl[i] += vv * wl;
                accr[i] += vv * wr;
            }
        }
        float bld = bl[d], brd = br[d];
        #pragma unroll
        for (int i = 0; i < 4; ++i) {
            xl_out[(size_t)(n0 + g * 4 + i) * 128 + d] = accl[i] + bld;
            xr_out[(size_t)(n0 + g * 4 + i) * 128 + d] = accr[i] + brd;
        }
    }
}

// ============================================================
// Kernel B: per-edge logits + dst histogram (+rank per edge)
// 16 edges per 256-thread block; 16 lanes per edge.
// ============================================================
__global__ __launch_bounds__(256) void edge_logits_kernel(
    const int* __restrict__ edge_index, const float* __restrict__ edge_attr,
    const float* __restrict__ We, const float* __restrict__ att,
    const float* __restrict__ xl, const float* __restrict__ xr,
    float* __restrict__ logits_out, unsigned* __restrict__ cnt,
    unsigned short* __restrict__ rank)
{
    __shared__ float We_s[ED_DIM * 128];  // 16 KB
    __shared__ float att_s[128];
    __shared__ float ea_s[16][33];
    const int tid = threadIdx.x;
    const int e0 = blockIdx.x * 16;

    for (int i = tid; i < ED_DIM * 128; i += 256) We_s[i] = We[i];
    if (tid < 128) att_s[tid] = att[tid];
    for (int i = tid; i < 16 * ED_DIM; i += 256)
        ea_s[i >> 5][i & 31] = edge_attr[(size_t)e0 * ED_DIM + i];
    __syncthreads();

    const int le = tid >> 4, l16 = tid & 15;
    const int e = e0 + le;
    const int src = edge_index[e];
    const int dst = edge_index[E_EDGES + e];
    const int d0 = l16 * 8;

    const float4* xlp = (const float4*)(xl + (size_t)src * 128 + d0);
    const float4* xrp = (const float4*)(xr + (size_t)dst * 128 + d0);
    float4 a0 = xlp[0], a1 = xlp[1];
    float4 r0 = xrp[0], r1 = xrp[1];
    float xv[8] = { a0.x + r0.x, a0.y + r0.y, a0.z + r0.z, a0.w + r0.w,
                    a1.x + r1.x, a1.y + r1.y, a1.z + r1.z, a1.w + r1.w };

    #pragma unroll 8
    for (int k = 0; k < ED_DIM; ++k) {
        float eak = ea_s[le][k];
        const float* Wrow = &We_s[k * 128 + d0];
        #pragma unroll
        for (int dd = 0; dd < 8; ++dd) xv[dd] += eak * Wrow[dd];
    }
    float p = 0.f;
    #pragma unroll
    for (int dd = 0; dd < 8; ++dd) {
        float x = xv[dd];
        x = (x > 0.f) ? x : 0.2f * x;
        p += x * att_s[d0 + dd];
    }
    p += __shfl_xor(p, 1);
    if ((l16 & 1) == 0) {
        logits_out[(size_t)e * 8 + (l16 >> 1)] = p;
    }
    if (l16 == 0) {
        unsigned rk = atomicAdd(&cnt[dst], 1u);
        rank[e] = (unsigned short)rk;
    }
}

// ============================================================
// Kernel S1: exclusive prefix sum of cnt[N] -> rowstart[N]
// single block, 1024 threads, Hillis-Steele per 1024-chunk.
// ============================================================
__global__ __launch_bounds__(1024) void scan_kernel(
    const unsigned* __restrict__ cnt, int* __restrict__ rowstart)
{
    __shared__ int buf[1024];
    __shared__ int s_carry;
    const int t = threadIdx.x;
    if (t == 0) s_carry = 0;
    __syncthreads();
    for (int base = 0; base < N_NODES; base += 1024) {
        int i = base + t;
        int v = (i < N_NODES) ? (int)cnt[i] : 0;
        buf[t] = v;
        __syncthreads();
        #pragma unroll
        for (int off = 1; off < 1024; off <<= 1) {
            int add = (t >= off) ? buf[t - off] : 0;
            __syncthreads();
            buf[t] += add;
            __syncthreads();
        }
        if (i < N_NODES) rowstart[i] = s_carry + buf[t] - v;
        __syncthreads();
        if (t == 0) s_carry += buf[1023];
        __syncthreads();
    }
}

// ============================================================
// Kernel S2: scatter edge ids into CSR order
// ============================================================
__global__ __launch_bounds__(256) void scatter_kernel(
    const int* __restrict__ edge_index, const unsigned short* __restrict__ rank,
    const int* __restrict__ rowstart, int* __restrict__ eidx)
{
    int e = blockIdx.x * 256 + threadIdx.x;
    if (e >= E_EDGES) return;
    int dst = edge_index[E_EDGES + e];
    eidx[rowstart[dst] + (int)rank[e]] = e;
}

// ============================================================
// Kernel C: per-node softmax + weighted aggregation + final LN
// one wave per node, 4 waves per 256-thread block. No atomics.
// alphabuf holds logits on entry; holds normalized alpha on exit.
// ============================================================
__global__ __launch_bounds__(256) void node_aggregate_kernel(
    const int* __restrict__ eidx, const int* __restrict__ rowstart,
    const unsigned* __restrict__ cnt, const int* __restrict__ edge_index,
    const float* __restrict__ xl, const float* __restrict__ v,
    const float* __restrict__ bias_out,
    const float* __restrict__ ln_g, const float* __restrict__ ln_b,
    float* __restrict__ alphabuf, float* __restrict__ out)
{
    const int wv = threadIdx.x >> 6, lane = threadIdx.x & 63;
    const int n = blockIdx.x * 4 + wv;
    if (n >= N_NODES) return;
    const int start = rowstart[n];
    const int num = (int)cnt[n];

    const int hh = lane & 7;      // head this lane reduces (passes 1-2,4)
    const int slot = lane >> 3;   // 8 edges in flight per iteration

    // ---- pass 1: per-head max over incoming edges ----
    float mx = -3.0e38f;
    for (int i = slot; i < num; i += 8) {
        int e = eidx[start + i];
        mx = fmaxf(mx, alphabuf[(size_t)e * 8 + hh]);
    }
    mx = fmaxf(mx, __shfl_xor(mx, 8));
    mx = fmaxf(mx, __shfl_xor(mx, 16));
    mx = fmaxf(mx, __shfl_xor(mx, 32));

    // ---- pass 2: per-head sum of exp ----
    float den = 0.f;
    for (int i = slot; i < num; i += 8) {
        int e = eidx[start + i];
        den += expf(alphabuf[(size_t)e * 8 + hh] - mx);
    }
    den += __shfl_xor(den, 8);
    den += __shfl_xor(den, 16);
    den += __shfl_xor(den, 32);
    float inv = 1.f / den;   // lanes 0..7 hold heads 0..7 (as do 8..15 etc.)

    // ---- pass 3: accumulate w = sum alpha * xl[src] ----
    const int h1 = lane >> 4;       // head of channel `lane`      (0..3)
    const int h2 = h1 + 4;          // head of channel `lane+64`   (4..7)
    float mx1 = __shfl(mx, h1), iv1 = __shfl(inv, h1);
    float mx2 = __shfl(mx, h2), iv2 = __shfl(inv, h2);
    float acc0 = 0.f, acc1 = 0.f;
    for (int i = 0; i < num; ++i) {
        int e = eidx[start + i];                  // broadcast load
        int src = edge_index[e];                  // broadcast load
        float lg1 = alphabuf[(size_t)e * 8 + h1];
        float lg2 = alphabuf[(size_t)e * 8 + h2];
        float a0 = expf(lg1 - mx1) * iv1;
        float a1 = expf(lg2 - mx2) * iv2;
        acc0 += xl[(size_t)src * 128 + lane] * a0;
        acc1 += xl[(size_t)src * 128 + lane + 64] * a1;
    }

    // drain all pass-3 loads before overwriting logits with alpha
    __builtin_amdgcn_s_waitcnt(0);

    // ---- pass 4: write normalized alpha over the logits ----
    for (int i = slot; i < num; i += 8) {
        int e = eidx[start + i];
        float lg = alphabuf[(size_t)e * 8 + hh];
        alphabuf[(size_t)e * 8 + hh] = expf(lg - mx) * inv;
    }

    // ---- epilogue: out = LN(w + bias_out + v) ----
    float x0 = acc0 + bias_out[lane]      + v[(size_t)n * 128 + lane];
    float x1 = acc1 + bias_out[lane + 64] + v[(size_t)n * 128 + lane + 64];
    float s = x0 + x1, ss = x0 * x0 + x1 * x1;
    #pragma unroll
    for (int off = 1; off < 64; off <<= 1) {
        s  += __shfl_xor(s, off);
        ss += __shfl_xor(ss, off);
    }
    float mu = s * (1.f / 128.f);
    float var = ss * (1.f / 128.f) - mu * mu;
    float rs = rsqrtf(var + 1e-5f);
    out[(size_t)n * 128 + lane]      = (x0 - mu) * rs * ln_g[lane]      + ln_b[lane];
    out[(size_t)n * 128 + lane + 64] = (x1 - mu) * rs * ln_g[lane + 64] + ln_b[lane + 64];
}

// ============================================================
extern "C" void kernel_launch(void* const* d_in, const int* in_sizes, int n_in,
                              void* d_out, int out_size, void* d_ws, size_t ws_size,
                              hipStream_t stream)
{
    const float* h        = (const float*)d_in[0];
    const int*   edge_idx = (const int*)  d_in[1];
    const float* edge_attr= (const float*)d_in[2];
    const float* w1       = (const float*)d_in[3];
    const float* b1       = (const float*)d_in[4];
    const float* w2       = (const float*)d_in[5];
    const float* b2       = (const float*)d_in[6];
    const float* ln_g     = (const float*)d_in[7];
    const float* ln_b     = (const float*)d_in[8];
    const float* Wl       = (const float*)d_in[9];
    const float* bl       = (const float*)d_in[10];
    const float* Wr       = (const float*)d_in[11];
    const float* br       = (const float*)d_in[12];
    const float* We       = (const float*)d_in[13];
    const float* att      = (const float*)d_in[14];
    const float* bias_out = (const float*)d_in[15];

    float* out   = (float*)d_out;                       // [N,128]
    float* alpha = out + (size_t)N_NODES * 128;         // [E,8] logits->alpha

    float*          v        = (float*)d_ws;                        // [N,128]
    float*          xl       = v  + (size_t)N_NODES * 128;          // [N,128]
    float*          xr       = xl + (size_t)N_NODES * 128;          // [N,128]
    unsigned*       cnt      = (unsigned*)(xr + (size_t)N_NODES * 128);  // [N]
    int*            rowstart = (int*)(cnt + N_NODES);               // [N]
    unsigned short* rank     = (unsigned short*)(rowstart + N_NODES); // [E]
    int*            eidx     = (int*)xr;  // aliases xr: written after xr's last read

    hipMemsetAsync(cnt, 0, (size_t)N_NODES * sizeof(unsigned), stream);

    node_ffn_kernel<<<N_NODES / 8, 256, 0, stream>>>(
        h, w1, b1, w2, b2, ln_g, ln_b, Wl, bl, Wr, br, v, xl, xr);
    edge_logits_kernel<<<E_EDGES / 16, 256, 0, stream>>>(
        edge_idx, edge_attr, We, att, xl, xr, alpha, cnt, rank);
    scan_kernel<<<1, 1024, 0, stream>>>(cnt, rowstart);
    scatter_kernel<<<(E_EDGES + 255) / 256, 256, 0, stream>>>(
        edge_idx, rank, rowstart, eidx);
    node_aggregate_kernel<<<(N_NODES + 3) / 4, 256, 0, stream>>>(
        eidx, rowstart, cnt, edge_idx, xl, v, bias_out, ln_g, ln_b, alpha, out);
}

// Round 3
// 707.542 us; speedup vs baseline: 5.1534x; 1.3965x over previous
//
#include <hip/hip_runtime.h>
#include <math.h>

#define N_NODES 50000
#define E_EDGES 800000
#define D_DIM   128
#define H_HEADS 8
#define C_CH    16
#define HID_DIM 512
#define ED_DIM  32

typedef __attribute__((ext_vector_type(8))) short short8;
typedef __attribute__((ext_vector_type(4))) float f32x4;

__device__ __forceinline__ short f2bf(float f) {
    unsigned u = __float_as_uint(f);
    return (short)((u + 0x7FFFu + ((u >> 16) & 1u)) >> 16);  // RNE
}

// ============================================================
// Kernel R: repack w1/w2/Wl/Wr (fp32 row-major [K][N]) into bf16
// B-fragment order for mfma_f32_16x16x32_bf16:
//   frag (t,c), lane l: 8 elems B[c*32+(l>>4)*8+j][t*16+(l&15)]
// flat short8 index = (t*(K/32)+c)*64 + l
// ============================================================
__global__ __launch_bounds__(64) void repack_kernel(
    const float* __restrict__ w1, const float* __restrict__ w2,
    const float* __restrict__ Wl, const float* __restrict__ Wr,
    short8* __restrict__ w1p, short8* __restrict__ w2p,
    short8* __restrict__ Wlp, short8* __restrict__ Wrp)
{
    int b = blockIdx.x;
    const float* src; short8* dst; int Nw, nc, rel;
    if (b < 128)      { src = w1; dst = w1p; Nw = 512; nc = 4;  rel = b; }
    else if (b < 256) { src = w2; dst = w2p; Nw = 128; nc = 16; rel = b - 128; }
    else if (b < 288) { src = Wl; dst = Wlp; Nw = 128; nc = 4;  rel = b - 256; }
    else              { src = Wr; dst = Wrp; Nw = 128; nc = 4;  rel = b - 288; }
    int t = rel / nc, c = rel % nc;
    int l = threadIdx.x, quad = l >> 4, col = l & 15;
    short8 r;
    #pragma unroll
    for (int j = 0; j < 8; ++j)
        r[j] = f2bf(src[(size_t)(c * 32 + quad * 8 + j) * Nw + t * 16 + col]);
    dst[(size_t)rel * 64 + l] = r;
}

// ============================================================
// Kernel A: MFMA node pipeline. 16 nodes/block, 256 thr (4 waves).
// hid = relu(h@w1+b1); u = hid@w2+b2; v = LN(h+u); xl/xr = v@Wl/Wr + b
// ============================================================
__global__ __launch_bounds__(256) void node_ffn_mfma(
    const float* __restrict__ h,
    const float* __restrict__ b1, const float* __restrict__ b2,
    const float* __restrict__ ln_g, const float* __restrict__ ln_b,
    const float* __restrict__ bl, const float* __restrict__ br,
    const short8* __restrict__ w1p, const short8* __restrict__ w2p,
    const short8* __restrict__ Wlp, const short8* __restrict__ Wrp,
    float* __restrict__ v_out, float* __restrict__ xl_out, float* __restrict__ xr_out)
{
    __shared__ short hid_bf[16 * 520];  // row stride 520 bf16 (260 w, %32=4)
    __shared__ float v_s[16 * 132];     // row stride 132 w (%32=4)
    __shared__ short v_bf[16 * 136];    // row stride 136 bf16 (68 w, %32=4)

    const int tid = threadIdx.x;
    const int w = tid >> 6, lane = tid & 63;
    const int m = lane & 15, quad = lane >> 4;
    const int n0 = blockIdx.x * 16;

    // ---- A1 fragments straight from h (fp32 -> bf16 in reg) ----
    short8 af[4];
    #pragma unroll
    for (int c = 0; c < 4; ++c) {
        const float* hp = h + (size_t)(n0 + m) * 128 + c * 32 + quad * 8;
        float4 p0 = ((const float4*)hp)[0];
        float4 p1 = ((const float4*)hp)[1];
        short8 a;
        a[0] = f2bf(p0.x); a[1] = f2bf(p0.y); a[2] = f2bf(p0.z); a[3] = f2bf(p0.w);
        a[4] = f2bf(p1.x); a[5] = f2bf(p1.y); a[6] = f2bf(p1.z); a[7] = f2bf(p1.w);
        af[c] = a;
    }

    // ---- matmul1: wave w computes hid cols [w*128, w*128+128) ----
    {
        f32x4 acc[8];
        #pragma unroll
        for (int t = 0; t < 8; ++t) acc[t] = (f32x4){0.f, 0.f, 0.f, 0.f};
        #pragma unroll
        for (int t = 0; t < 8; ++t) {
            int tile = w * 8 + t;
            #pragma unroll
            for (int c = 0; c < 4; ++c) {
                short8 bf = w1p[(size_t)(tile * 4 + c) * 64 + lane];
                acc[t] = __builtin_amdgcn_mfma_f32_16x16x32_bf16(af[c], bf, acc[t], 0, 0, 0);
            }
        }
        #pragma unroll
        for (int t = 0; t < 8; ++t) {
            int col = (w * 8 + t) * 16 + m;
            float bias = b1[col];
            #pragma unroll
            for (int r = 0; r < 4; ++r) {
                int row = quad * 4 + r;
                hid_bf[row * 520 + col] = f2bf(fmaxf(acc[t][r] + bias, 0.f));
            }
        }
    }
    __syncthreads();

    // ---- matmul2: u = hid@w2; wave w cols [w*32, w*32+32) ----
    {
        f32x4 acc2[2];
        acc2[0] = (f32x4){0.f, 0.f, 0.f, 0.f};
        acc2[1] = (f32x4){0.f, 0.f, 0.f, 0.f};
        #pragma unroll 4
        for (int c = 0; c < 16; ++c) {
            short8 a = *(const short8*)&hid_bf[m * 520 + c * 32 + quad * 8];
            #pragma unroll
            for (int t = 0; t < 2; ++t) {
                short8 bf = w2p[(size_t)((w * 2 + t) * 16 + c) * 64 + lane];
                acc2[t] = __builtin_amdgcn_mfma_f32_16x16x32_bf16(a, bf, acc2[t], 0, 0, 0);
            }
        }
        #pragma unroll
        for (int t = 0; t < 2; ++t) {
            int col = (w * 2 + t) * 16 + m;
            float bias = b2[col];
            #pragma unroll
            for (int r = 0; r < 4; ++r) {
                int row = quad * 4 + r;
                v_s[row * 132 + col] = acc2[t][r] + bias + h[(size_t)(n0 + row) * 128 + col];
            }
        }
    }
    __syncthreads();

    // ---- LayerNorm: wave w handles nodes 4w..4w+3 ----
    {
        float g0 = ln_g[lane], g1 = ln_g[lane + 64];
        float be0 = ln_b[lane], be1 = ln_b[lane + 64];
        #pragma unroll
        for (int p = 0; p < 4; ++p) {
            int nd = w * 4 + p;
            float x0 = v_s[nd * 132 + lane], x1 = v_s[nd * 132 + lane + 64];
            float s = x0 + x1, ss = x0 * x0 + x1 * x1;
            #pragma unroll
            for (int off = 1; off < 64; off <<= 1) {
                s  += __shfl_xor(s, off);
                ss += __shfl_xor(ss, off);
            }
            float mu = s * (1.f / 128.f);
            float var = ss * (1.f / 128.f) - mu * mu;
            float rs = rsqrtf(var + 1e-5f);
            float y0 = (x0 - mu) * rs * g0 + be0;
            float y1 = (x1 - mu) * rs * g1 + be1;
            v_out[(size_t)(n0 + nd) * 128 + lane]      = y0;
            v_out[(size_t)(n0 + nd) * 128 + lane + 64] = y1;
            v_bf[nd * 136 + lane]      = f2bf(y0);
            v_bf[nd * 136 + lane + 64] = f2bf(y1);
        }
    }
    __syncthreads();

    // ---- matmul3: xl/xr; wave w cols [w*32, w*32+32) ----
    {
        short8 af3[4];
        #pragma unroll
        for (int c = 0; c < 4; ++c)
            af3[c] = *(const short8*)&v_bf[m * 136 + c * 32 + quad * 8];
        f32x4 accl[2], accr[2];
        #pragma unroll
        for (int t = 0; t < 2; ++t) {
            accl[t] = (f32x4){0.f, 0.f, 0.f, 0.f};
            accr[t] = (f32x4){0.f, 0.f, 0.f, 0.f};
        }
        #pragma unroll
        for (int t = 0; t < 2; ++t) {
            int tile = w * 2 + t;
            #pragma unroll
            for (int c = 0; c < 4; ++c) {
                accl[t] = __builtin_amdgcn_mfma_f32_16x16x32_bf16(
                    af3[c], Wlp[(size_t)(tile * 4 + c) * 64 + lane], accl[t], 0, 0, 0);
                accr[t] = __builtin_amdgcn_mfma_f32_16x16x32_bf16(
                    af3[c], Wrp[(size_t)(tile * 4 + c) * 64 + lane], accr[t], 0, 0, 0);
            }
        }
        #pragma unroll
        for (int t = 0; t < 2; ++t) {
            int col = (w * 2 + t) * 16 + m;
            float bld = bl[col], brd = br[col];
            #pragma unroll
            for (int r = 0; r < 4; ++r) {
                int row = quad * 4 + r;
                xl_out[(size_t)(n0 + row) * 128 + col] = accl[t][r] + bld;
                xr_out[(size_t)(n0 + row) * 128 + col] = accr[t][r] + brd;
            }
        }
    }
}

// ============================================================
// Kernel B: per-edge logits + dst histogram (+rank per edge)
// ============================================================
__global__ __launch_bounds__(256) void edge_logits_kernel(
    const int* __restrict__ edge_index, const float* __restrict__ edge_attr,
    const float* __restrict__ We, const float* __restrict__ att,
    const float* __restrict__ xl, const float* __restrict__ xr,
    float* __restrict__ logits_out, unsigned* __restrict__ cnt,
    unsigned short* __restrict__ rank)
{
    __shared__ float We_s[ED_DIM * 128];
    __shared__ float att_s[128];
    __shared__ float ea_s[16][33];
    const int tid = threadIdx.x;
    const int e0 = blockIdx.x * 16;

    for (int i = tid; i < ED_DIM * 128; i += 256) We_s[i] = We[i];
    if (tid < 128) att_s[tid] = att[tid];
    for (int i = tid; i < 16 * ED_DIM; i += 256)
        ea_s[i >> 5][i & 31] = edge_attr[(size_t)e0 * ED_DIM + i];
    __syncthreads();

    const int le = tid >> 4, l16 = tid & 15;
    const int e = e0 + le;
    const int src = edge_index[e];
    const int dst = edge_index[E_EDGES + e];
    const int d0 = l16 * 8;

    const float4* xlp = (const float4*)(xl + (size_t)src * 128 + d0);
    const float4* xrp = (const float4*)(xr + (size_t)dst * 128 + d0);
    float4 a0 = xlp[0], a1 = xlp[1];
    float4 r0 = xrp[0], r1 = xrp[1];
    float xv[8] = { a0.x + r0.x, a0.y + r0.y, a0.z + r0.z, a0.w + r0.w,
                    a1.x + r1.x, a1.y + r1.y, a1.z + r1.z, a1.w + r1.w };

    #pragma unroll 8
    for (int k = 0; k < ED_DIM; ++k) {
        float eak = ea_s[le][k];
        const float* Wrow = &We_s[k * 128 + d0];
        #pragma unroll
        for (int dd = 0; dd < 8; ++dd) xv[dd] += eak * Wrow[dd];
    }
    float p = 0.f;
    #pragma unroll
    for (int dd = 0; dd < 8; ++dd) {
        float x = xv[dd];
        x = (x > 0.f) ? x : 0.2f * x;
        p += x * att_s[d0 + dd];
    }
    p += __shfl_xor(p, 1);
    if ((l16 & 1) == 0) {
        logits_out[(size_t)e * 8 + (l16 >> 1)] = p;
    }
    if (l16 == 0) {
        unsigned rk = atomicAdd(&cnt[dst], 1u);
        rank[e] = (unsigned short)rk;
    }
}

// ============================================================
// Kernel S1: exclusive scan via per-wave shfl scans (2 barriers/chunk)
// ============================================================
__global__ __launch_bounds__(1024) void scan_kernel(
    const unsigned* __restrict__ cnt, int* __restrict__ rowstart)
{
    __shared__ int wsum[16];
    __shared__ int s_carry;
    const int t = threadIdx.x, wv = t >> 6, lane = t & 63;
    if (t == 0) s_carry = 0;
    __syncthreads();
    for (int base = 0; base < N_NODES; base += 1024) {
        int i = base + t;
        int v = (i < N_NODES) ? (int)cnt[i] : 0;
        int s = v;
        #pragma unroll
        for (int off = 1; off < 64; off <<= 1) {
            int nb = __shfl_up(s, off);
            if (lane >= off) s += nb;
        }
        if (lane == 63) wsum[wv] = s;
        __syncthreads();
        int woff = s_carry;
        for (int k = 0; k < wv; ++k) woff += wsum[k];
        if (i < N_NODES) rowstart[i] = woff + s - v;
        int tot = woff + s;                 // chunk total at t==1023
        __syncthreads();
        if (t == 1023) s_carry = tot;
    }
}

// ============================================================
// Kernel S2: scatter edge ids into CSR order
// ============================================================
__global__ __launch_bounds__(256) void scatter_kernel(
    const int* __restrict__ edge_index, const unsigned short* __restrict__ rank,
    const int* __restrict__ rowstart, int* __restrict__ eidx)
{
    int e = blockIdx.x * 256 + threadIdx.x;
    if (e >= E_EDGES) return;
    int dst = edge_index[E_EDGES + e];
    eidx[rowstart[dst] + (int)rank[e]] = e;
}

// ============================================================
// Kernel C: per-node softmax + aggregation + final LN (no atomics)
// ============================================================
__global__ __launch_bounds__(256) void node_aggregate_kernel(
    const int* __restrict__ eidx, const int* __restrict__ rowstart,
    const unsigned* __restrict__ cnt, const int* __restrict__ edge_index,
    const float* __restrict__ xl, const float* __restrict__ v,
    const float* __restrict__ bias_out,
    const float* __restrict__ ln_g, const float* __restrict__ ln_b,
    float* __restrict__ alphabuf, float* __restrict__ out)
{
    const int wv = threadIdx.x >> 6, lane = threadIdx.x & 63;
    const int n = blockIdx.x * 4 + wv;
    if (n >= N_NODES) return;
    const int start = rowstart[n];
    const int num = (int)cnt[n];

    const int hh = lane & 7;
    const int slot = lane >> 3;

    float mx = -3.0e38f;
    for (int i = slot; i < num; i += 8) {
        int e = eidx[start + i];
        mx = fmaxf(mx, alphabuf[(size_t)e * 8 + hh]);
    }
    mx = fmaxf(mx, __shfl_xor(mx, 8));
    mx = fmaxf(mx, __shfl_xor(mx, 16));
    mx = fmaxf(mx, __shfl_xor(mx, 32));

    float den = 0.f;
    for (int i = slot; i < num; i += 8) {
        int e = eidx[start + i];
        den += expf(alphabuf[(size_t)e * 8 + hh] - mx);
    }
    den += __shfl_xor(den, 8);
    den += __shfl_xor(den, 16);
    den += __shfl_xor(den, 32);
    float inv = 1.f / den;

    const int h1 = lane >> 4;
    const int h2 = h1 + 4;
    float mx1 = __shfl(mx, h1), iv1 = __shfl(inv, h1);
    float mx2 = __shfl(mx, h2), iv2 = __shfl(inv, h2);
    float acc0 = 0.f, acc1 = 0.f;
    for (int i = 0; i < num; ++i) {
        int e = eidx[start + i];
        int src = edge_index[e];
        float lg1 = alphabuf[(size_t)e * 8 + h1];
        float lg2 = alphabuf[(size_t)e * 8 + h2];
        float a0 = expf(lg1 - mx1) * iv1;
        float a1 = expf(lg2 - mx2) * iv2;
        acc0 += xl[(size_t)src * 128 + lane] * a0;
        acc1 += xl[(size_t)src * 128 + lane + 64] * a1;
    }

    __builtin_amdgcn_s_waitcnt(0);

    for (int i = slot; i < num; i += 8) {
        int e = eidx[start + i];
        float lg = alphabuf[(size_t)e * 8 + hh];
        alphabuf[(size_t)e * 8 + hh] = expf(lg - mx) * inv;
    }

    float x0 = acc0 + bias_out[lane]      + v[(size_t)n * 128 + lane];
    float x1 = acc1 + bias_out[lane + 64] + v[(size_t)n * 128 + lane + 64];
    float s = x0 + x1, ss = x0 * x0 + x1 * x1;
    #pragma unroll
    for (int off = 1; off < 64; off <<= 1) {
        s  += __shfl_xor(s, off);
        ss += __shfl_xor(ss, off);
    }
    float mu = s * (1.f / 128.f);
    float var = ss * (1.f / 128.f) - mu * mu;
    float rs = rsqrtf(var + 1e-5f);
    out[(size_t)n * 128 + lane]      = (x0 - mu) * rs * ln_g[lane]      + ln_b[lane];
    out[(size_t)n * 128 + lane + 64] = (x1 - mu) * rs * ln_g[lane + 64] + ln_b[lane + 64];
}

// ============================================================
extern "C" void kernel_launch(void* const* d_in, const int* in_sizes, int n_in,
                              void* d_out, int out_size, void* d_ws, size_t ws_size,
                              hipStream_t stream)
{
    const float* h        = (const float*)d_in[0];
    const int*   edge_idx = (const int*)  d_in[1];
    const float* edge_attr= (const float*)d_in[2];
    const float* w1       = (const float*)d_in[3];
    const float* b1       = (const float*)d_in[4];
    const float* w2       = (const float*)d_in[5];
    const float* b2       = (const float*)d_in[6];
    const float* ln_g     = (const float*)d_in[7];
    const float* ln_b     = (const float*)d_in[8];
    const float* Wl       = (const float*)d_in[9];
    const float* bl       = (const float*)d_in[10];
    const float* Wr       = (const float*)d_in[11];
    const float* br       = (const float*)d_in[12];
    const float* We       = (const float*)d_in[13];
    const float* att      = (const float*)d_in[14];
    const float* bias_out = (const float*)d_in[15];

    float* out   = (float*)d_out;                       // [N,128]
    float* alpha = out + (size_t)N_NODES * 128;         // [E,8] logits->alpha

    // packed bf16 weights live at the START of the alpha region; they are
    // fully consumed by node_ffn_mfma BEFORE edge_logits overwrites alpha.
    short8* w1p = (short8*)alpha;                       // 128 KB
    short8* w2p = w1p + 128 * 64;                       // 128 KB
    short8* Wlp = w2p + 128 * 64;                       // 32 KB
    short8* Wrp = Wlp + 32 * 64;                        // 32 KB

    float*          v        = (float*)d_ws;                          // [N,128]
    float*          xl       = v  + (size_t)N_NODES * 128;            // [N,128]
    float*          xr       = xl + (size_t)N_NODES * 128;            // [N,128]
    unsigned*       cnt      = (unsigned*)(xr + (size_t)N_NODES * 128);  // [N]
    int*            rowstart = (int*)(cnt + N_NODES);                 // [N]
    unsigned short* rank     = (unsigned short*)(rowstart + N_NODES); // [E]
    int*            eidx     = (int*)xr;  // aliases xr (dead after edge_logits)

    hipMemsetAsync(cnt, 0, (size_t)N_NODES * sizeof(unsigned), stream);

    repack_kernel<<<320, 64, 0, stream>>>(w1, w2, Wl, Wr, w1p, w2p, Wlp, Wrp);
    node_ffn_mfma<<<N_NODES / 16, 256, 0, stream>>>(
        h, b1, b2, ln_g, ln_b, bl, br, w1p, w2p, Wlp, Wrp, v, xl, xr);
    edge_logits_kernel<<<E_EDGES / 16, 256, 0, stream>>>(
        edge_idx, edge_attr, We, att, xl, xr, alpha, cnt, rank);
    scan_kernel<<<1, 1024, 0, stream>>>(cnt, rowstart);
    scatter_kernel<<<(E_EDGES + 255) / 256, 256, 0, stream>>>(
        edge_idx, rank, rowstart, eidx);
    node_aggregate_kernel<<<(N_NODES + 3) / 4, 256, 0, stream>>>(
        eidx, rowstart, cnt, edge_idx, xl, v, bias_out, ln_g, ln_b, alpha, out);
}

// Round 4
// 564.398 us; speedup vs baseline: 6.4604x; 1.2536x over previous
//
#include <hip/hip_runtime.h>
#include <math.h>

#define N_NODES 50000
#define E_EDGES 800000
#define D_DIM   128
#define H_HEADS 8
#define C_CH    16
#define HID_DIM 512
#define ED_DIM  32

typedef __attribute__((ext_vector_type(8))) short short8;
typedef __attribute__((ext_vector_type(4))) float f32x4;

__device__ __forceinline__ short f2bf(float f) {
    unsigned u = __float_as_uint(f);
    return (short)((u + 0x7FFFu + ((u >> 16) & 1u)) >> 16);  // RNE
}

// ============================================================
// Kernel R: repack w1/w2/Wl/Wr (fp32 row-major [K][N]) into bf16
// B-fragment order for mfma_f32_16x16x32_bf16.
// ============================================================
__global__ __launch_bounds__(64) void repack_kernel(
    const float* __restrict__ w1, const float* __restrict__ w2,
    const float* __restrict__ Wl, const float* __restrict__ Wr,
    short8* __restrict__ w1p, short8* __restrict__ w2p,
    short8* __restrict__ Wlp, short8* __restrict__ Wrp)
{
    int b = blockIdx.x;
    const float* src; short8* dst; int Nw, nc, rel;
    if (b < 128)      { src = w1; dst = w1p; Nw = 512; nc = 4;  rel = b; }
    else if (b < 256) { src = w2; dst = w2p; Nw = 128; nc = 16; rel = b - 128; }
    else if (b < 288) { src = Wl; dst = Wlp; Nw = 128; nc = 4;  rel = b - 256; }
    else              { src = Wr; dst = Wrp; Nw = 128; nc = 4;  rel = b - 288; }
    int t = rel / nc, c = rel % nc;
    int l = threadIdx.x, quad = l >> 4, col = l & 15;
    short8 r;
    #pragma unroll
    for (int j = 0; j < 8; ++j)
        r[j] = f2bf(src[(size_t)(c * 32 + quad * 8 + j) * Nw + t * 16 + col]);
    dst[(size_t)rel * 64 + l] = r;
}

// ============================================================
// Kernel A: MFMA node pipeline. 16 nodes/block, 256 thr (4 waves).
// ============================================================
__global__ __launch_bounds__(256) void node_ffn_mfma(
    const float* __restrict__ h,
    const float* __restrict__ b1, const float* __restrict__ b2,
    const float* __restrict__ ln_g, const float* __restrict__ ln_b,
    const float* __restrict__ bl, const float* __restrict__ br,
    const short8* __restrict__ w1p, const short8* __restrict__ w2p,
    const short8* __restrict__ Wlp, const short8* __restrict__ Wrp,
    float* __restrict__ v_out, float* __restrict__ xl_out, float* __restrict__ xr_out)
{
    __shared__ short hid_bf[16 * 520];
    __shared__ float v_s[16 * 132];
    __shared__ short v_bf[16 * 136];

    const int tid = threadIdx.x;
    const int w = tid >> 6, lane = tid & 63;
    const int m = lane & 15, quad = lane >> 4;
    const int n0 = blockIdx.x * 16;

    short8 af[4];
    #pragma unroll
    for (int c = 0; c < 4; ++c) {
        const float* hp = h + (size_t)(n0 + m) * 128 + c * 32 + quad * 8;
        float4 p0 = ((const float4*)hp)[0];
        float4 p1 = ((const float4*)hp)[1];
        short8 a;
        a[0] = f2bf(p0.x); a[1] = f2bf(p0.y); a[2] = f2bf(p0.z); a[3] = f2bf(p0.w);
        a[4] = f2bf(p1.x); a[5] = f2bf(p1.y); a[6] = f2bf(p1.z); a[7] = f2bf(p1.w);
        af[c] = a;
    }

    {
        f32x4 acc[8];
        #pragma unroll
        for (int t = 0; t < 8; ++t) acc[t] = (f32x4){0.f, 0.f, 0.f, 0.f};
        #pragma unroll
        for (int t = 0; t < 8; ++t) {
            int tile = w * 8 + t;
            #pragma unroll
            for (int c = 0; c < 4; ++c) {
                short8 bf = w1p[(size_t)(tile * 4 + c) * 64 + lane];
                acc[t] = __builtin_amdgcn_mfma_f32_16x16x32_bf16(af[c], bf, acc[t], 0, 0, 0);
            }
        }
        #pragma unroll
        for (int t = 0; t < 8; ++t) {
            int col = (w * 8 + t) * 16 + m;
            float bias = b1[col];
            #pragma unroll
            for (int r = 0; r < 4; ++r) {
                int row = quad * 4 + r;
                hid_bf[row * 520 + col] = f2bf(fmaxf(acc[t][r] + bias, 0.f));
            }
        }
    }
    __syncthreads();

    {
        f32x4 acc2[2];
        acc2[0] = (f32x4){0.f, 0.f, 0.f, 0.f};
        acc2[1] = (f32x4){0.f, 0.f, 0.f, 0.f};
        #pragma unroll 4
        for (int c = 0; c < 16; ++c) {
            short8 a = *(const short8*)&hid_bf[m * 520 + c * 32 + quad * 8];
            #pragma unroll
            for (int t = 0; t < 2; ++t) {
                short8 bf = w2p[(size_t)((w * 2 + t) * 16 + c) * 64 + lane];
                acc2[t] = __builtin_amdgcn_mfma_f32_16x16x32_bf16(a, bf, acc2[t], 0, 0, 0);
            }
        }
        #pragma unroll
        for (int t = 0; t < 2; ++t) {
            int col = (w * 2 + t) * 16 + m;
            float bias = b2[col];
            #pragma unroll
            for (int r = 0; r < 4; ++r) {
                int row = quad * 4 + r;
                v_s[row * 132 + col] = acc2[t][r] + bias + h[(size_t)(n0 + row) * 128 + col];
            }
        }
    }
    __syncthreads();

    {
        float g0 = ln_g[lane], g1 = ln_g[lane + 64];
        float be0 = ln_b[lane], be1 = ln_b[lane + 64];
        #pragma unroll
        for (int p = 0; p < 4; ++p) {
            int nd = w * 4 + p;
            float x0 = v_s[nd * 132 + lane], x1 = v_s[nd * 132 + lane + 64];
            float s = x0 + x1, ss = x0 * x0 + x1 * x1;
            #pragma unroll
            for (int off = 1; off < 64; off <<= 1) {
                s  += __shfl_xor(s, off);
                ss += __shfl_xor(ss, off);
            }
            float mu = s * (1.f / 128.f);
            float var = ss * (1.f / 128.f) - mu * mu;
            float rs = rsqrtf(var + 1e-5f);
            float y0 = (x0 - mu) * rs * g0 + be0;
            float y1 = (x1 - mu) * rs * g1 + be1;
            v_out[(size_t)(n0 + nd) * 128 + lane]      = y0;
            v_out[(size_t)(n0 + nd) * 128 + lane + 64] = y1;
            v_bf[nd * 136 + lane]      = f2bf(y0);
            v_bf[nd * 136 + lane + 64] = f2bf(y1);
        }
    }
    __syncthreads();

    {
        short8 af3[4];
        #pragma unroll
        for (int c = 0; c < 4; ++c)
            af3[c] = *(const short8*)&v_bf[m * 136 + c * 32 + quad * 8];
        f32x4 accl[2], accr[2];
        #pragma unroll
        for (int t = 0; t < 2; ++t) {
            accl[t] = (f32x4){0.f, 0.f, 0.f, 0.f};
            accr[t] = (f32x4){0.f, 0.f, 0.f, 0.f};
        }
        #pragma unroll
        for (int t = 0; t < 2; ++t) {
            int tile = w * 2 + t;
            #pragma unroll
            for (int c = 0; c < 4; ++c) {
                accl[t] = __builtin_amdgcn_mfma_f32_16x16x32_bf16(
                    af3[c], Wlp[(size_t)(tile * 4 + c) * 64 + lane], accl[t], 0, 0, 0);
                accr[t] = __builtin_amdgcn_mfma_f32_16x16x32_bf16(
                    af3[c], Wrp[(size_t)(tile * 4 + c) * 64 + lane], accr[t], 0, 0, 0);
            }
        }
        #pragma unroll
        for (int t = 0; t < 2; ++t) {
            int col = (w * 2 + t) * 16 + m;
            float bld = bl[col], brd = br[col];
            #pragma unroll
            for (int r = 0; r < 4; ++r) {
                int row = quad * 4 + r;
                xl_out[(size_t)(n0 + row) * 128 + col] = accl[t][r] + bld;
                xr_out[(size_t)(n0 + row) * 128 + col] = accr[t][r] + brd;
            }
        }
    }
}

// ============================================================
// Kernel B: edge logits via MFMA xe + gathers. 64 edges/block.
// ============================================================
__global__ __launch_bounds__(256) void edge_logits_mfma(
    const int* __restrict__ edge_index, const float* __restrict__ edge_attr,
    const float* __restrict__ We, const float* __restrict__ att,
    const float* __restrict__ xl, const float* __restrict__ xr,
    float* __restrict__ logits_out, unsigned* __restrict__ cnt,
    unsigned short* __restrict__ rank)
{
    __shared__ short8 We_f[512];       // 8 KB, B-frag order
    __shared__ float xe_s[64 * 132];   // 33.8 KB, padded stride
    const int tid = threadIdx.x;
    const int w = tid >> 6, lane = tid & 63;
    const int m = lane & 15, quad = lane >> 4;
    const int e0 = blockIdx.x * 64;

    // stage We as bf16 B-fragments (8 col-tiles, K=32)
    #pragma unroll
    for (int ii = 0; ii < 2; ++ii) {
        int idx = tid + ii * 256;
        int t = idx >> 6, l = idx & 63;
        int q = l >> 4, c = l & 15;
        short8 b;
        #pragma unroll
        for (int j = 0; j < 8; ++j)
            b[j] = f2bf(We[(q * 8 + j) * 128 + t * 16 + c]);
        We_f[idx] = b;
    }

    // A-frag straight from edge_attr (wave w owns edge-tile w)
    const float* eap = edge_attr + (size_t)(e0 + w * 16 + m) * 32 + quad * 8;
    float4 p0 = ((const float4*)eap)[0];
    float4 p1 = ((const float4*)eap)[1];
    short8 a;
    a[0] = f2bf(p0.x); a[1] = f2bf(p0.y); a[2] = f2bf(p0.z); a[3] = f2bf(p0.w);
    a[4] = f2bf(p1.x); a[5] = f2bf(p1.y); a[6] = f2bf(p1.z); a[7] = f2bf(p1.w);

    __syncthreads();

    // xe = ea @ We : 8 MFMAs per wave (one per 16-col tile)
    f32x4 acc[8];
    #pragma unroll
    for (int t = 0; t < 8; ++t) acc[t] = (f32x4){0.f, 0.f, 0.f, 0.f};
    #pragma unroll
    for (int t = 0; t < 8; ++t)
        acc[t] = __builtin_amdgcn_mfma_f32_16x16x32_bf16(a, We_f[t * 64 + lane], acc[t], 0, 0, 0);

    #pragma unroll
    for (int t = 0; t < 8; ++t) {
        #pragma unroll
        for (int r = 0; r < 4; ++r)
            xe_s[(w * 16 + quad * 4 + r) * 132 + t * 16 + m] = acc[t][r];
    }
    __syncthreads();

    // per-edge phase: wave handles 4 edges/pass; lane = (g=quad-sel)*16 + s
    const int g = quad;          // edge selector 0..3
    const int s = m;             // channel-slot 0..15
    const int d0 = s * 8;
    float4 at0 = ((const float4*)(att + d0))[0];
    float4 at1 = ((const float4*)(att + d0))[1];

    #pragma unroll
    for (int p = 0; p < 4; ++p) {
        int el = p * 16 + w * 4 + g;
        int e = e0 + el;
        int src = edge_index[e];
        int dst = edge_index[E_EDGES + e];
        const float4* xlp = (const float4*)(xl + (size_t)src * 128 + d0);
        const float4* xrp = (const float4*)(xr + (size_t)dst * 128 + d0);
        float4 a0 = xlp[0], a1 = xlp[1];
        float4 r0 = xrp[0], r1 = xrp[1];
        const float* xep = &xe_s[el * 132 + d0];
        float4 x0 = ((const float4*)xep)[0];
        float4 x1 = ((const float4*)xep)[1];

        float xv[8] = { a0.x + r0.x + x0.x, a0.y + r0.y + x0.y,
                        a0.z + r0.z + x0.z, a0.w + r0.w + x0.w,
                        a1.x + r1.x + x1.x, a1.y + r1.y + x1.y,
                        a1.z + r1.z + x1.z, a1.w + r1.w + x1.w };
        float atv[8] = { at0.x, at0.y, at0.z, at0.w, at1.x, at1.y, at1.z, at1.w };
        float pq = 0.f;
        #pragma unroll
        for (int dd = 0; dd < 8; ++dd) {
            float x = xv[dd];
            x = (x > 0.f) ? x : 0.2f * x;
            pq += x * atv[dd];
        }
        pq += __shfl_xor(pq, 1);
        if ((s & 1) == 0)
            logits_out[(size_t)e * 8 + (s >> 1)] = pq;
        if (s == 0) {
            unsigned rk = atomicAdd(&cnt[dst], 1u);
            rank[e] = (unsigned short)rk;
        }
    }
}

// ============================================================
// Kernel S1: exclusive scan via per-wave shfl scans
// ============================================================
__global__ __launch_bounds__(1024) void scan_kernel(
    const unsigned* __restrict__ cnt, int* __restrict__ rowstart)
{
    __shared__ int wsum[16];
    __shared__ int s_carry;
    const int t = threadIdx.x, wv = t >> 6, lane = t & 63;
    if (t == 0) s_carry = 0;
    __syncthreads();
    for (int base = 0; base < N_NODES; base += 1024) {
        int i = base + t;
        int v = (i < N_NODES) ? (int)cnt[i] : 0;
        int s = v;
        #pragma unroll
        for (int off = 1; off < 64; off <<= 1) {
            int nb = __shfl_up(s, off);
            if (lane >= off) s += nb;
        }
        if (lane == 63) wsum[wv] = s;
        __syncthreads();
        int woff = s_carry;
        for (int k = 0; k < wv; ++k) woff += wsum[k];
        if (i < N_NODES) rowstart[i] = woff + s - v;
        int tot = woff + s;
        __syncthreads();
        if (t == 1023) s_carry = tot;
    }
}

// ============================================================
// Kernel S2: scatter edge ids into CSR order
// ============================================================
__global__ __launch_bounds__(256) void scatter_kernel(
    const int* __restrict__ edge_index, const unsigned short* __restrict__ rank,
    const int* __restrict__ rowstart, int* __restrict__ eidx)
{
    int e = blockIdx.x * 256 + threadIdx.x;
    if (e >= E_EDGES) return;
    int dst = edge_index[E_EDGES + e];
    eidx[rowstart[dst] + (int)rank[e]] = e;
}

// ============================================================
// Kernel C: per-node softmax + aggregation + final LN (no atomics)
// pass 3 runs 4 edges in flight for memory-level parallelism.
// ============================================================
__global__ __launch_bounds__(256) void node_aggregate_kernel(
    const int* __restrict__ eidx, const int* __restrict__ rowstart,
    const unsigned* __restrict__ cnt, const int* __restrict__ edge_index,
    const float* __restrict__ xl, const float* __restrict__ v,
    const float* __restrict__ bias_out,
    const float* __restrict__ ln_g, const float* __restrict__ ln_b,
    float* __restrict__ alphabuf, float* __restrict__ out)
{
    const int wv = threadIdx.x >> 6, lane = threadIdx.x & 63;
    const int n = blockIdx.x * 4 + wv;
    if (n >= N_NODES) return;
    const int start = rowstart[n];
    const int num = (int)cnt[n];

    const int hh = lane & 7;
    const int slot = lane >> 3;

    // pass 1: per-head max
    float mx = -3.0e38f;
    for (int i = slot; i < num; i += 8) {
        int e = eidx[start + i];
        mx = fmaxf(mx, alphabuf[(size_t)e * 8 + hh]);
    }
    mx = fmaxf(mx, __shfl_xor(mx, 8));
    mx = fmaxf(mx, __shfl_xor(mx, 16));
    mx = fmaxf(mx, __shfl_xor(mx, 32));

    // pass 2: denominator
    float den = 0.f;
    for (int i = slot; i < num; i += 8) {
        int e = eidx[start + i];
        den += expf(alphabuf[(size_t)e * 8 + hh] - mx);
    }
    den += __shfl_xor(den, 8);
    den += __shfl_xor(den, 16);
    den += __shfl_xor(den, 32);
    float inv = 1.f / den;

    // pass 3: 4 edges in flight; lane = g*16 + s, channels s*8..s*8+7
    const int g = lane >> 4, s = lane & 15;
    const int h3 = s >> 1;
    float mx3 = __shfl(mx, h3), iv3 = __shfl(inv, h3);
    float acc[8] = {0.f, 0.f, 0.f, 0.f, 0.f, 0.f, 0.f, 0.f};
    for (int i = 0; i < num; i += 4) {
        int ii = i + g;
        if (ii < num) {
            int e = eidx[start + ii];
            int src = edge_index[e];
            float al = expf(alphabuf[(size_t)e * 8 + h3] - mx3) * iv3;
            const float4* xp = (const float4*)(xl + (size_t)src * 128 + s * 8);
            float4 q0 = xp[0], q1 = xp[1];
            acc[0] += q0.x * al; acc[1] += q0.y * al;
            acc[2] += q0.z * al; acc[3] += q0.w * al;
            acc[4] += q1.x * al; acc[5] += q1.y * al;
            acc[6] += q1.z * al; acc[7] += q1.w * al;
        }
    }
    #pragma unroll
    for (int k = 0; k < 8; ++k) {
        acc[k] += __shfl_xor(acc[k], 16);
        acc[k] += __shfl_xor(acc[k], 32);
    }

    __builtin_amdgcn_s_waitcnt(0);

    // pass 4: write normalized alpha over the logits
    for (int i = slot; i < num; i += 8) {
        int e = eidx[start + i];
        float lg = alphabuf[(size_t)e * 8 + hh];
        alphabuf[(size_t)e * 8 + hh] = expf(lg - mx) * inv;
    }

    // epilogue: LN(w + bias_out + v); lane s holds channels s*8..s*8+7
    const float* vp = v + (size_t)n * 128 + s * 8;
    float4 v0 = ((const float4*)vp)[0], v1 = ((const float4*)vp)[1];
    float4 b0 = ((const float4*)(bias_out + s * 8))[0];
    float4 b1 = ((const float4*)(bias_out + s * 8))[1];
    float x[8];
    x[0] = acc[0] + b0.x + v0.x; x[1] = acc[1] + b0.y + v0.y;
    x[2] = acc[2] + b0.z + v0.z; x[3] = acc[3] + b0.w + v0.w;
    x[4] = acc[4] + b1.x + v1.x; x[5] = acc[5] + b1.y + v1.y;
    x[6] = acc[6] + b1.z + v1.z; x[7] = acc[7] + b1.w + v1.w;
    float sm = 0.f, ssm = 0.f;
    #pragma unroll
    for (int k = 0; k < 8; ++k) { sm += x[k]; ssm += x[k] * x[k]; }
    #pragma unroll
    for (int off = 1; off < 16; off <<= 1) {
        sm  += __shfl_xor(sm, off);
        ssm += __shfl_xor(ssm, off);
    }
    float mu = sm * (1.f / 128.f);
    float var = ssm * (1.f / 128.f) - mu * mu;
    float rs = rsqrtf(var + 1e-5f);
    if (g == 0) {
        float4 g0 = ((const float4*)(ln_g + s * 8))[0];
        float4 g1 = ((const float4*)(ln_g + s * 8))[1];
        float4 be0 = ((const float4*)(ln_b + s * 8))[0];
        float4 be1 = ((const float4*)(ln_b + s * 8))[1];
        float4 o0, o1;
        o0.x = (x[0] - mu) * rs * g0.x + be0.x;
        o0.y = (x[1] - mu) * rs * g0.y + be0.y;
        o0.z = (x[2] - mu) * rs * g0.z + be0.z;
        o0.w = (x[3] - mu) * rs * g0.w + be0.w;
        o1.x = (x[4] - mu) * rs * g1.x + be1.x;
        o1.y = (x[5] - mu) * rs * g1.y + be1.y;
        o1.z = (x[6] - mu) * rs * g1.z + be1.z;
        o1.w = (x[7] - mu) * rs * g1.w + be1.w;
        float4* op = (float4*)(out + (size_t)n * 128 + s * 8);
        op[0] = o0; op[1] = o1;
    }
}

// ============================================================
extern "C" void kernel_launch(void* const* d_in, const int* in_sizes, int n_in,
                              void* d_out, int out_size, void* d_ws, size_t ws_size,
                              hipStream_t stream)
{
    const float* h        = (const float*)d_in[0];
    const int*   edge_idx = (const int*)  d_in[1];
    const float* edge_attr= (const float*)d_in[2];
    const float* w1       = (const float*)d_in[3];
    const float* b1       = (const float*)d_in[4];
    const float* w2       = (const float*)d_in[5];
    const float* b2       = (const float*)d_in[6];
    const float* ln_g     = (const float*)d_in[7];
    const float* ln_b     = (const float*)d_in[8];
    const float* Wl       = (const float*)d_in[9];
    const float* bl       = (const float*)d_in[10];
    const float* Wr       = (const float*)d_in[11];
    const float* br       = (const float*)d_in[12];
    const float* We       = (const float*)d_in[13];
    const float* att      = (const float*)d_in[14];
    const float* bias_out = (const float*)d_in[15];

    float* out   = (float*)d_out;                       // [N,128]
    float* alpha = out + (size_t)N_NODES * 128;         // [E,8] logits->alpha

    short8* w1p = (short8*)alpha;                       // packed weights live in
    short8* w2p = w1p + 128 * 64;                       // alpha region, consumed
    short8* Wlp = w2p + 128 * 64;                       // before edge_logits
    short8* Wrp = Wlp + 32 * 64;                        // overwrites it

    float*          v        = (float*)d_ws;                          // [N,128]
    float*          xl       = v  + (size_t)N_NODES * 128;            // [N,128]
    float*          xr       = xl + (size_t)N_NODES * 128;            // [N,128]
    unsigned*       cnt      = (unsigned*)(xr + (size_t)N_NODES * 128);  // [N]
    int*            rowstart = (int*)(cnt + N_NODES);                 // [N]
    unsigned short* rank     = (unsigned short*)(rowstart + N_NODES); // [E]
    int*            eidx     = (int*)xr;  // aliases xr (dead after edge_logits)

    hipMemsetAsync(cnt, 0, (size_t)N_NODES * sizeof(unsigned), stream);

    repack_kernel<<<320, 64, 0, stream>>>(w1, w2, Wl, Wr, w1p, w2p, Wlp, Wrp);
    node_ffn_mfma<<<N_NODES / 16, 256, 0, stream>>>(
        h, b1, b2, ln_g, ln_b, bl, br, w1p, w2p, Wlp, Wrp, v, xl, xr);
    edge_logits_mfma<<<E_EDGES / 64, 256, 0, stream>>>(
        edge_idx, edge_attr, We, att, xl, xr, alpha, cnt, rank);
    scan_kernel<<<1, 1024, 0, stream>>>(cnt, rowstart);
    scatter_kernel<<<(E_EDGES + 255) / 256, 256, 0, stream>>>(
        edge_idx, rank, rowstart, eidx);
    node_aggregate_kernel<<<(N_NODES + 3) / 4, 256, 0, stream>>>(
        eidx, rowstart, cnt, edge_idx, xl, v, bias_out, ln_g, ln_b, alpha, out);
}

// Round 5
// 529.202 us; speedup vs baseline: 6.8901x; 1.0665x over previous
//
#include <hip/hip_runtime.h>
#include <math.h>

#define N_NODES 50000
#define E_EDGES 800000
#define D_DIM   128
#define H_HEADS 8
#define C_CH    16
#define HID_DIM 512
#define ED_DIM  32

typedef __attribute__((ext_vector_type(8))) short short8;
typedef __attribute__((ext_vector_type(4))) float f32x4;

__device__ __forceinline__ short f2bf(float f) {
    unsigned u = __float_as_uint(f);
    return (short)((u + 0x7FFFu + ((u >> 16) & 1u)) >> 16);  // RNE
}
__device__ __forceinline__ float bf2f(short s) {
    return __uint_as_float(((unsigned)(unsigned short)s) << 16);
}

// ============================================================
// Kernel R: repack w1/w2/Wl/Wr/We (fp32 [K][N]) into bf16
// B-fragment order for mfma_f32_16x16x32_bf16.
// ============================================================
__global__ __launch_bounds__(64) void repack_kernel(
    const float* __restrict__ w1, const float* __restrict__ w2,
    const float* __restrict__ Wl, const float* __restrict__ Wr,
    const float* __restrict__ We,
    short8* __restrict__ w1p, short8* __restrict__ w2p,
    short8* __restrict__ Wlp, short8* __restrict__ Wrp,
    short8* __restrict__ Wep)
{
    int b = blockIdx.x;
    const float* src; short8* dst; int Nw, nc, rel;
    if (b < 128)      { src = w1; dst = w1p; Nw = 512; nc = 4;  rel = b; }
    else if (b < 256) { src = w2; dst = w2p; Nw = 128; nc = 16; rel = b - 128; }
    else if (b < 288) { src = Wl; dst = Wlp; Nw = 128; nc = 4;  rel = b - 256; }
    else if (b < 320) { src = Wr; dst = Wrp; Nw = 128; nc = 4;  rel = b - 288; }
    else              { src = We; dst = Wep; Nw = 128; nc = 1;  rel = b - 320; }
    int t = rel / nc, c = rel % nc;
    int l = threadIdx.x, quad = l >> 4, col = l & 15;
    short8 r;
    #pragma unroll
    for (int j = 0; j < 8; ++j)
        r[j] = f2bf(src[(size_t)(c * 32 + quad * 8 + j) * Nw + t * 16 + col]);
    dst[(size_t)rel * 64 + l] = r;
}

// ============================================================
// Kernel A: MFMA node pipeline. 16 nodes/block, 256 thr (4 waves).
// ============================================================
__global__ __launch_bounds__(256) void node_ffn_mfma(
    const float* __restrict__ h,
    const float* __restrict__ b1, const float* __restrict__ b2,
    const float* __restrict__ ln_g, const float* __restrict__ ln_b,
    const float* __restrict__ bl, const float* __restrict__ br,
    const short8* __restrict__ w1p, const short8* __restrict__ w2p,
    const short8* __restrict__ Wlp, const short8* __restrict__ Wrp,
    float* __restrict__ v_out, float* __restrict__ xl_out, float* __restrict__ xr_out)
{
    __shared__ short hid_bf[16 * 520];
    __shared__ float v_s[16 * 132];
    __shared__ short v_bf[16 * 136];

    const int tid = threadIdx.x;
    const int w = tid >> 6, lane = tid & 63;
    const int m = lane & 15, quad = lane >> 4;
    const int n0 = blockIdx.x * 16;

    short8 af[4];
    #pragma unroll
    for (int c = 0; c < 4; ++c) {
        const float* hp = h + (size_t)(n0 + m) * 128 + c * 32 + quad * 8;
        float4 p0 = ((const float4*)hp)[0];
        float4 p1 = ((const float4*)hp)[1];
        short8 a;
        a[0] = f2bf(p0.x); a[1] = f2bf(p0.y); a[2] = f2bf(p0.z); a[3] = f2bf(p0.w);
        a[4] = f2bf(p1.x); a[5] = f2bf(p1.y); a[6] = f2bf(p1.z); a[7] = f2bf(p1.w);
        af[c] = a;
    }

    {
        f32x4 acc[8];
        #pragma unroll
        for (int t = 0; t < 8; ++t) acc[t] = (f32x4){0.f, 0.f, 0.f, 0.f};
        #pragma unroll
        for (int t = 0; t < 8; ++t) {
            int tile = w * 8 + t;
            #pragma unroll
            for (int c = 0; c < 4; ++c) {
                short8 bf = w1p[(size_t)(tile * 4 + c) * 64 + lane];
                acc[t] = __builtin_amdgcn_mfma_f32_16x16x32_bf16(af[c], bf, acc[t], 0, 0, 0);
            }
        }
        #pragma unroll
        for (int t = 0; t < 8; ++t) {
            int col = (w * 8 + t) * 16 + m;
            float bias = b1[col];
            #pragma unroll
            for (int r = 0; r < 4; ++r) {
                int row = quad * 4 + r;
                hid_bf[row * 520 + col] = f2bf(fmaxf(acc[t][r] + bias, 0.f));
            }
        }
    }
    __syncthreads();

    {
        f32x4 acc2[2];
        acc2[0] = (f32x4){0.f, 0.f, 0.f, 0.f};
        acc2[1] = (f32x4){0.f, 0.f, 0.f, 0.f};
        #pragma unroll 4
        for (int c = 0; c < 16; ++c) {
            short8 a = *(const short8*)&hid_bf[m * 520 + c * 32 + quad * 8];
            #pragma unroll
            for (int t = 0; t < 2; ++t) {
                short8 bf = w2p[(size_t)((w * 2 + t) * 16 + c) * 64 + lane];
                acc2[t] = __builtin_amdgcn_mfma_f32_16x16x32_bf16(a, bf, acc2[t], 0, 0, 0);
            }
        }
        #pragma unroll
        for (int t = 0; t < 2; ++t) {
            int col = (w * 2 + t) * 16 + m;
            float bias = b2[col];
            #pragma unroll
            for (int r = 0; r < 4; ++r) {
                int row = quad * 4 + r;
                v_s[row * 132 + col] = acc2[t][r] + bias + h[(size_t)(n0 + row) * 128 + col];
            }
        }
    }
    __syncthreads();

    {
        float g0 = ln_g[lane], g1 = ln_g[lane + 64];
        float be0 = ln_b[lane], be1 = ln_b[lane + 64];
        #pragma unroll
        for (int p = 0; p < 4; ++p) {
            int nd = w * 4 + p;
            float x0 = v_s[nd * 132 + lane], x1 = v_s[nd * 132 + lane + 64];
            float s = x0 + x1, ss = x0 * x0 + x1 * x1;
            #pragma unroll
            for (int off = 1; off < 64; off <<= 1) {
                s  += __shfl_xor(s, off);
                ss += __shfl_xor(ss, off);
            }
            float mu = s * (1.f / 128.f);
            float var = ss * (1.f / 128.f) - mu * mu;
            float rs = rsqrtf(var + 1e-5f);
            float y0 = (x0 - mu) * rs * g0 + be0;
            float y1 = (x1 - mu) * rs * g1 + be1;
            v_out[(size_t)(n0 + nd) * 128 + lane]      = y0;
            v_out[(size_t)(n0 + nd) * 128 + lane + 64] = y1;
            v_bf[nd * 136 + lane]      = f2bf(y0);
            v_bf[nd * 136 + lane + 64] = f2bf(y1);
        }
    }
    __syncthreads();

    {
        short8 af3[4];
        #pragma unroll
        for (int c = 0; c < 4; ++c)
            af3[c] = *(const short8*)&v_bf[m * 136 + c * 32 + quad * 8];
        f32x4 accl[2], accr[2];
        #pragma unroll
        for (int t = 0; t < 2; ++t) {
            accl[t] = (f32x4){0.f, 0.f, 0.f, 0.f};
            accr[t] = (f32x4){0.f, 0.f, 0.f, 0.f};
        }
        #pragma unroll
        for (int t = 0; t < 2; ++t) {
            int tile = w * 2 + t;
            #pragma unroll
            for (int c = 0; c < 4; ++c) {
                accl[t] = __builtin_amdgcn_mfma_f32_16x16x32_bf16(
                    af3[c], Wlp[(size_t)(tile * 4 + c) * 64 + lane], accl[t], 0, 0, 0);
                accr[t] = __builtin_amdgcn_mfma_f32_16x16x32_bf16(
                    af3[c], Wrp[(size_t)(tile * 4 + c) * 64 + lane], accr[t], 0, 0, 0);
            }
        }
        #pragma unroll
        for (int t = 0; t < 2; ++t) {
            int col = (w * 2 + t) * 16 + m;
            float bld = bl[col], brd = br[col];
            #pragma unroll
            for (int r = 0; r < 4; ++r) {
                int row = quad * 4 + r;
                xl_out[(size_t)(n0 + row) * 128 + col] = accl[t][r] + bld;
                xr_out[(size_t)(n0 + row) * 128 + col] = accr[t][r] + brd;
            }
        }
    }
}

// ============================================================
// Kernel B: edge logits via MFMA xe + gathers. 64 edges/block.
// xe parked in LDS as bf16 -> 26 KB LDS -> 6 blocks/CU.
// ============================================================
__global__ __launch_bounds__(256) void edge_logits_mfma(
    const int* __restrict__ edge_index, const float* __restrict__ edge_attr,
    const short8* __restrict__ Wep, const float* __restrict__ att,
    const float* __restrict__ xl, const float* __restrict__ xr,
    float* __restrict__ logits_out, unsigned* __restrict__ cnt,
    unsigned short* __restrict__ rank)
{
    __shared__ short8 We_f[512];       // 8 KB, B-frag order
    __shared__ short xe_s[64 * 136];   // 17 KB bf16, stride 136 (272 B, 16B-aligned)
    const int tid = threadIdx.x;
    const int w = tid >> 6, lane = tid & 63;
    const int m = lane & 15, quad = lane >> 4;
    const int e0 = blockIdx.x * 64;

    // stage pre-packed We fragments (coalesced 16 B loads)
    We_f[tid]       = Wep[tid];
    We_f[tid + 256] = Wep[tid + 256];

    // A-frag straight from edge_attr (wave w owns edge-tile w)
    const float* eap = edge_attr + (size_t)(e0 + w * 16 + m) * 32 + quad * 8;
    float4 p0 = ((const float4*)eap)[0];
    float4 p1 = ((const float4*)eap)[1];
    short8 a;
    a[0] = f2bf(p0.x); a[1] = f2bf(p0.y); a[2] = f2bf(p0.z); a[3] = f2bf(p0.w);
    a[4] = f2bf(p1.x); a[5] = f2bf(p1.y); a[6] = f2bf(p1.z); a[7] = f2bf(p1.w);

    __syncthreads();

    // xe = ea @ We : 8 MFMAs per wave
    f32x4 acc[8];
    #pragma unroll
    for (int t = 0; t < 8; ++t) acc[t] = (f32x4){0.f, 0.f, 0.f, 0.f};
    #pragma unroll
    for (int t = 0; t < 8; ++t)
        acc[t] = __builtin_amdgcn_mfma_f32_16x16x32_bf16(a, We_f[t * 64 + lane], acc[t], 0, 0, 0);

    #pragma unroll
    for (int t = 0; t < 8; ++t) {
        #pragma unroll
        for (int r = 0; r < 4; ++r)
            xe_s[(w * 16 + quad * 4 + r) * 136 + t * 16 + m] = f2bf(acc[t][r]);
    }
    __syncthreads();

    // per-edge phase: 4 edges/pass per wave; lane = g*16 + s
    const int g = quad;
    const int s = m;
    const int d0 = s * 8;
    float4 at0 = ((const float4*)(att + d0))[0];
    float4 at1 = ((const float4*)(att + d0))[1];

    #pragma unroll
    for (int p = 0; p < 4; ++p) {
        int el = p * 16 + w * 4 + g;
        int e = e0 + el;
        int src = edge_index[e];
        int dst = edge_index[E_EDGES + e];
        const float4* xlp = (const float4*)(xl + (size_t)src * 128 + d0);
        const float4* xrp = (const float4*)(xr + (size_t)dst * 128 + d0);
        float4 a0 = xlp[0], a1 = xlp[1];
        float4 r0 = xrp[0], r1 = xrp[1];
        short8 xe8 = *(const short8*)&xe_s[el * 136 + d0];

        float xv[8] = { a0.x + r0.x + bf2f(xe8[0]), a0.y + r0.y + bf2f(xe8[1]),
                        a0.z + r0.z + bf2f(xe8[2]), a0.w + r0.w + bf2f(xe8[3]),
                        a1.x + r1.x + bf2f(xe8[4]), a1.y + r1.y + bf2f(xe8[5]),
                        a1.z + r1.z + bf2f(xe8[6]), a1.w + r1.w + bf2f(xe8[7]) };
        float atv[8] = { at0.x, at0.y, at0.z, at0.w, at1.x, at1.y, at1.z, at1.w };
        float pq = 0.f;
        #pragma unroll
        for (int dd = 0; dd < 8; ++dd) {
            float x = xv[dd];
            x = (x > 0.f) ? x : 0.2f * x;
            pq += x * atv[dd];
        }
        pq += __shfl_xor(pq, 1);
        if ((s & 1) == 0)
            logits_out[(size_t)e * 8 + (s >> 1)] = pq;
        if (s == 0) {
            unsigned rk = atomicAdd(&cnt[dst], 1u);
            rank[e] = (unsigned short)rk;
        }
    }
}

// ============================================================
// Kernel S1: exclusive scan via per-wave shfl scans
// ============================================================
__global__ __launch_bounds__(1024) void scan_kernel(
    const unsigned* __restrict__ cnt, int* __restrict__ rowstart)
{
    __shared__ int wsum[16];
    __shared__ int s_carry;
    const int t = threadIdx.x, wv = t >> 6, lane = t & 63;
    if (t == 0) s_carry = 0;
    __syncthreads();
    for (int base = 0; base < N_NODES; base += 1024) {
        int i = base + t;
        int v = (i < N_NODES) ? (int)cnt[i] : 0;
        int s = v;
        #pragma unroll
        for (int off = 1; off < 64; off <<= 1) {
            int nb = __shfl_up(s, off);
            if (lane >= off) s += nb;
        }
        if (lane == 63) wsum[wv] = s;
        __syncthreads();
        int woff = s_carry;
        for (int k = 0; k < wv; ++k) woff += wsum[k];
        if (i < N_NODES) rowstart[i] = woff + s - v;
        int tot = woff + s;
        __syncthreads();
        if (t == 1023) s_carry = tot;
    }
}

// ============================================================
// Kernel S2: scatter edge ids into CSR order
// ============================================================
__global__ __launch_bounds__(256) void scatter_kernel(
    const int* __restrict__ edge_index, const unsigned short* __restrict__ rank,
    const int* __restrict__ rowstart, int* __restrict__ eidx)
{
    int e = blockIdx.x * 256 + threadIdx.x;
    if (e >= E_EDGES) return;
    int dst = edge_index[E_EDGES + e];
    eidx[rowstart[dst] + (int)rank[e]] = e;
}

// ============================================================
// Kernel C: per-node softmax + aggregation + final LN (no atomics)
// Softmax without max-subtraction (logits bounded; identical math):
//   pass A: den = sum exp(lg); pass B: msg accumulate + alpha write.
// ============================================================
__global__ __launch_bounds__(256) void node_aggregate_kernel(
    const int* __restrict__ eidx, const int* __restrict__ rowstart,
    const unsigned* __restrict__ cnt, const int* __restrict__ edge_index,
    const float* __restrict__ xl, const float* __restrict__ v,
    const float* __restrict__ bias_out,
    const float* __restrict__ ln_g, const float* __restrict__ ln_b,
    float* __restrict__ alphabuf, float* __restrict__ out)
{
    const int wv = threadIdx.x >> 6, lane = threadIdx.x & 63;
    const int n = blockIdx.x * 4 + wv;
    if (n >= N_NODES) return;
    const int start = rowstart[n];
    const int num = (int)cnt[n];

    const int hh = lane & 7;
    const int slot = lane >> 3;

    // pass A: denominator (8 edges in flight per head)
    float den = 0.f;
    for (int i = slot; i < num; i += 8) {
        int e = eidx[start + i];
        den += expf(alphabuf[(size_t)e * 8 + hh]);
    }
    den += __shfl_xor(den, 8);
    den += __shfl_xor(den, 16);
    den += __shfl_xor(den, 32);
    float inv = 1.f / den;   // lane L holds inv for head L&7

    // pass B: 4 edges in flight; lane = g*16 + s, channels s*8..s*8+7
    const int g = lane >> 4, s = lane & 15;
    const int h3 = s >> 1;
    float iv3 = __shfl(inv, h3);
    float acc[8] = {0.f, 0.f, 0.f, 0.f, 0.f, 0.f, 0.f, 0.f};
    for (int i = 0; i < num; i += 4) {
        int ii = i + g;
        if (ii < num) {
            int e = eidx[start + ii];
            int src = edge_index[e];
            float lg = alphabuf[(size_t)e * 8 + h3];
            float al = expf(lg) * iv3;
            if ((s & 1) == 0) alphabuf[(size_t)e * 8 + h3] = al;  // fused alpha write
            const float4* xp = (const float4*)(xl + (size_t)src * 128 + s * 8);
            float4 q0 = xp[0], q1 = xp[1];
            acc[0] += q0.x * al; acc[1] += q0.y * al;
            acc[2] += q0.z * al; acc[3] += q0.w * al;
            acc[4] += q1.x * al; acc[5] += q1.y * al;
            acc[6] += q1.z * al; acc[7] += q1.w * al;
        }
    }
    #pragma unroll
    for (int k = 0; k < 8; ++k) {
        acc[k] += __shfl_xor(acc[k], 16);
        acc[k] += __shfl_xor(acc[k], 32);
    }

    // epilogue: LN(w + bias_out + v); lane s holds channels s*8..s*8+7
    const float* vp = v + (size_t)n * 128 + s * 8;
    float4 v0 = ((const float4*)vp)[0], v1 = ((const float4*)vp)[1];
    float4 b0 = ((const float4*)(bias_out + s * 8))[0];
    float4 b1 = ((const float4*)(bias_out + s * 8))[1];
    float x[8];
    x[0] = acc[0] + b0.x + v0.x; x[1] = acc[1] + b0.y + v0.y;
    x[2] = acc[2] + b0.z + v0.z; x[3] = acc[3] + b0.w + v0.w;
    x[4] = acc[4] + b1.x + v1.x; x[5] = acc[5] + b1.y + v1.y;
    x[6] = acc[6] + b1.z + v1.z; x[7] = acc[7] + b1.w + v1.w;
    float sm = 0.f, ssm = 0.f;
    #pragma unroll
    for (int k = 0; k < 8; ++k) { sm += x[k]; ssm += x[k] * x[k]; }
    #pragma unroll
    for (int off = 1; off < 16; off <<= 1) {
        sm  += __shfl_xor(sm, off);
        ssm += __shfl_xor(ssm, off);
    }
    float mu = sm * (1.f / 128.f);
    float var = ssm * (1.f / 128.f) - mu * mu;
    float rs = rsqrtf(var + 1e-5f);
    if (g == 0) {
        float4 g0 = ((const float4*)(ln_g + s * 8))[0];
        float4 g1 = ((const float4*)(ln_g + s * 8))[1];
        float4 be0 = ((const float4*)(ln_b + s * 8))[0];
        float4 be1 = ((const float4*)(ln_b + s * 8))[1];
        float4 o0, o1;
        o0.x = (x[0] - mu) * rs * g0.x + be0.x;
        o0.y = (x[1] - mu) * rs * g0.y + be0.y;
        o0.z = (x[2] - mu) * rs * g0.z + be0.z;
        o0.w = (x[3] - mu) * rs * g0.w + be0.w;
        o1.x = (x[4] - mu) * rs * g1.x + be1.x;
        o1.y = (x[5] - mu) * rs * g1.y + be1.y;
        o1.z = (x[6] - mu) * rs * g1.z + be1.z;
        o1.w = (x[7] - mu) * rs * g1.w + be1.w;
        float4* op = (float4*)(out + (size_t)n * 128 + s * 8);
        op[0] = o0; op[1] = o1;
    }
}

// ============================================================
extern "C" void kernel_launch(void* const* d_in, const int* in_sizes, int n_in,
                              void* d_out, int out_size, void* d_ws, size_t ws_size,
                              hipStream_t stream)
{
    const float* h        = (const float*)d_in[0];
    const int*   edge_idx = (const int*)  d_in[1];
    const float* edge_attr= (const float*)d_in[2];
    const float* w1       = (const float*)d_in[3];
    const float* b1       = (const float*)d_in[4];
    const float* w2       = (const float*)d_in[5];
    const float* b2       = (const float*)d_in[6];
    const float* ln_g     = (const float*)d_in[7];
    const float* ln_b     = (const float*)d_in[8];
    const float* Wl       = (const float*)d_in[9];
    const float* bl       = (const float*)d_in[10];
    const float* Wr       = (const float*)d_in[11];
    const float* br       = (const float*)d_in[12];
    const float* We       = (const float*)d_in[13];
    const float* att      = (const float*)d_in[14];
    const float* bias_out = (const float*)d_in[15];

    float* out   = (float*)d_out;                       // [N,128]
    float* alpha = out + (size_t)N_NODES * 128;         // [E,8] logits->alpha

    short8* w1p = (short8*)alpha;                       // packed weights live in
    short8* w2p = w1p + 128 * 64;                       // alpha region, consumed by
    short8* Wlp = w2p + 128 * 64;                       // node_ffn BEFORE edge_logits
    short8* Wrp = Wlp + 32 * 64;                        // overwrites them

    float*          v        = (float*)d_ws;                          // [N,128]
    float*          xl       = v  + (size_t)N_NODES * 128;            // [N,128]
    float*          xr       = xl + (size_t)N_NODES * 128;            // [N,128]
    unsigned*       cnt      = (unsigned*)(xr + (size_t)N_NODES * 128);  // [N]
    int*            rowstart = (int*)(cnt + N_NODES);                 // [N]
    unsigned short* rank     = (unsigned short*)(rowstart + N_NODES); // [E]
    short8*         Wep      = (short8*)(rank + E_EDGES);             // [512] 8 KB
    int*            eidx     = (int*)xr;  // aliases xr (dead after edge_logits)

    hipMemsetAsync(cnt, 0, (size_t)N_NODES * sizeof(unsigned), stream);

    repack_kernel<<<328, 64, 0, stream>>>(w1, w2, Wl, Wr, We,
                                          w1p, w2p, Wlp, Wrp, Wep);
    node_ffn_mfma<<<N_NODES / 16, 256, 0, stream>>>(
        h, b1, b2, ln_g, ln_b, bl, br, w1p, w2p, Wlp, Wrp, v, xl, xr);
    edge_logits_mfma<<<E_EDGES / 64, 256, 0, stream>>>(
        edge_idx, edge_attr, Wep, att, xl, xr, alpha, cnt, rank);
    scan_kernel<<<1, 1024, 0, stream>>>(cnt, rowstart);
    scatter_kernel<<<(E_EDGES + 255) / 256, 256, 0, stream>>>(
        edge_idx, rank, rowstart, eidx);
    node_aggregate_kernel<<<(N_NODES + 3) / 4, 256, 0, stream>>>(
        eidx, rowstart, cnt, edge_idx, xl, v, bias_out, ln_g, ln_b, alpha, out);
}